// Round 6
// baseline (13809.297 us; speedup 1.0000x reference)
//
#include <hip/hip_runtime.h>
#include <hip/hip_cooperative_groups.h>
#include <stdint.h>

namespace cg = cooperative_groups;

#define NBATCH 128
#define NNEUR  4096
#define TLAST  180                      // outputs depend only on steps 0..180
#define DECAY  0.6065306597126334f      // float(exp(-0.5))
#define SCOPE  __HIP_MEMORY_SCOPE_AGENT

// ONE cooperative kernel runs all 181 steps (grid.sync per step).
// Grid: 512 blocks = 128 batches x 4 column tiles (1024 cols); 2 blocks/CU
// co-resident. Block: 256 threads = 4 waves; wave owns 256 cols, 4/lane (float4).
// volts / rec / window sums live in REGISTERS for the entire simulation; the
// only global state is the double-buffered spike bitmask (agent-scope atomics).
// Gather add order is ascending row index -> bitwise-identical to round 1.
__global__ __launch_bounds__(256, 2) void lif_all(
    const float* __restrict__ ff, const float* __restrict__ W,
    const float* __restrict__ rec0, float* __restrict__ out,
    unsigned long long* __restrict__ bits)   // 2 x [128][64] u64
{
#pragma clang fp contract(off)          // match numpy's separate mul/add roundings
    cg::grid_group grid = cg::this_grid();

    __shared__ __align__(16) unsigned short slist[NNEUR];
    __shared__ int scnt;

    const int tid  = threadIdx.x;
    const int lane = tid & 63;
    const int wid  = tid >> 6;
    const int bid  = blockIdx.x;
    const int b    = bid >> 2;                        // batch
    const int tile = bid & 3;
    const int c0   = (tile << 10) + (wid << 8);       // wave's 256-col base
    const int n0   = c0 + (lane << 2);                // lane's 4 columns
    const unsigned laneb = (unsigned)n0 * 4u;         // byte offset within a W row

    const char*  Wb   = (const char*)W;
    const float* fptr = ff + (((size_t)b * 200) << 12) + n0;
    const size_t idx  = ((size_t)b << 12) + (size_t)n0;

    float4 v4 = make_float4(0.f, 0.f, 0.f, 0.f);      // volts (regs, whole run)
    float4 r4 = *(const float4*)(rec0 + idx);         // rec
    float4 ss = v4, sv = v4;                          // window sums

    for (int t = 0; t <= TLAST; ++t) {
        const float4 f4 = *(const float4*)fptr;       // independent: overlaps gather
        fptr += NNEUR;

        float4 acc = make_float4(0.f, 0.f, 0.f, 0.f);
        if (t > 0) {
            // ---- decode batch's spike bitmask into LDS index list (wave 0) ----
            const unsigned long long* bsrc =
                bits + (((size_t)((t - 1) & 1)) << 13) + (b << 6);
            if (wid == 0) {
                unsigned long long m =
                    __hip_atomic_load(&bsrc[lane], __ATOMIC_RELAXED, SCOPE);
                const int c = __popcll(m);
                int x = c;
                #pragma unroll
                for (int o = 1; o < 64; o <<= 1) {
                    int y = __shfl_up(x, (unsigned)o);
                    if (lane >= o) x += y;
                }
                if (lane == 63) scnt = x;
                int widx = x - c;                               // exclusive prefix
                const int jb = ((lane >> 2) << 8) + (lane & 3); // word's col base
                while (m) {
                    const int u = __builtin_ctzll(m);
                    m &= m - 1;
                    slist[widx++] = (unsigned short)(jb + (u << 2));
                }
            }
            __syncthreads();

            // ---- sparse gather, 8-deep double-buffered pipeline (R3 loop) ----
            const int cnt = scnt;
            auto load8 = [&](float4* R, int ii) {
                const uint4 pk = *(const uint4*)(slist + ii);
                unsigned q[4];
                q[0] = pk.x; q[1] = pk.y; q[2] = pk.z; q[3] = pk.w;
                #pragma unroll
                for (int k = 0; k < 4; ++k) {
                    const unsigned qq = __builtin_amdgcn_readfirstlane(q[k]);
                    R[2 * k]     = *(const float4*)(Wb + (((qq & 0xffffu) << 14) + laneb));
                    R[2 * k + 1] = *(const float4*)(Wb + (((qq >> 16)     << 14) + laneb));
                }
            };
            auto acc8 = [&](const float4* R) {
                #pragma unroll
                for (int k = 0; k < 8; ++k) {
                    acc.x += R[k].x; acc.y += R[k].y;
                    acc.z += R[k].z; acc.w += R[k].w;
                }
            };

            int i = 0;
            if (cnt >= 8) {
                float4 A[8], B[8];
                load8(A, 0); i = 8;
                while (i + 16 <= cnt) {
                    load8(B, i);     acc8(A);
                    load8(A, i + 8); acc8(B);
                    i += 16;
                }
                if (i + 8 <= cnt) { load8(B, i); acc8(A); acc8(B); i += 8; }
                else              { acc8(A); }
            }
            for (; i < cnt; ++i) {
                unsigned q = (unsigned)slist[i];
                q = __builtin_amdgcn_readfirstlane(q);
                const float4 wv = *(const float4*)(Wb + ((q << 14) + laneb));
                acc.x += wv.x; acc.y += wv.y; acc.z += wv.z; acc.w += wv.w;
            }
        }

        // ---- elementwise LIF update (exact numpy op order) ----
        r4.x = r4.x * DECAY + acc.x * 0.5f;
        r4.y = r4.y * DECAY + acc.y * 0.5f;
        r4.z = r4.z * DECAY + acc.z * 0.5f;
        r4.w = r4.w * DECAY + acc.w * 0.5f;

        v4.x = v4.x * DECAY + 0.5f * (f4.x + r4.x);
        v4.y = v4.y * DECAY + 0.5f * (f4.y + r4.y);
        v4.z = v4.z * DECAY + 0.5f * (f4.z + r4.z);
        v4.w = v4.w * DECAY + 0.5f * (f4.w + r4.w);

        const bool s0 = v4.x >= 1.0f, s1 = v4.y >= 1.0f,
                   s2 = v4.z >= 1.0f, s3 = v4.w >= 1.0f;
        if (s0) v4.x = 0.f;
        if (s1) v4.y = 0.f;
        if (s2) v4.z = 0.f;
        if (s3) v4.w = 0.f;

        // ---- publish new spike bitmask (agent scope, all XCDs) ----
        const unsigned long long m0 = __ballot(s0), m1 = __ballot(s1),
                                 m2 = __ballot(s2), m3 = __ballot(s3);
        if (t < TLAST && lane == 0) {
            unsigned long long* dst =
                bits + (((size_t)(t & 1)) << 13) + (b << 6) + (c0 >> 6);
            __hip_atomic_store(&dst[0], m0, __ATOMIC_RELAXED, SCOPE);
            __hip_atomic_store(&dst[1], m1, __ATOMIC_RELAXED, SCOPE);
            __hip_atomic_store(&dst[2], m2, __ATOMIC_RELAXED, SCOPE);
            __hip_atomic_store(&dst[3], m3, __ATOMIC_RELAXED, SCOPE);
        }

        // ---- recording windows (sums in registers) ----
        if (t >= 80) {
            const float4 s4 = make_float4(s0 ? 1.f : 0.f, s1 ? 1.f : 0.f,
                                          s2 ? 1.f : 0.f, s3 ? 1.f : 0.f);
            const bool start = (t == 80) || (t == 101) || (t == 121) ||
                               (t == 141) || (t == 161);
            if (start) {
                ss = s4; sv = v4;
            } else {
                ss.x += s4.x; ss.y += s4.y; ss.z += s4.z; ss.w += s4.w;
                sv.x += v4.x; sv.y += v4.y; sv.z += v4.z; sv.w += v4.w;
            }
            if (t == 100 || t == 120 || t == 140 || t == 160 || t == 180) {
                const int k = (t - 100) / 20;
                const size_t oidx = (((size_t)b * 5 + (size_t)k) << 12) + n0;
                float* rates = out;
                float* vavg  = out + (size_t)NBATCH * 5 * NNEUR;
                float* srec  = out + (size_t)NBATCH * 5 * NNEUR * 2;
                *(float4*)(rates + oidx) = make_float4(ss.x / 20.f, ss.y / 20.f,
                                                       ss.z / 20.f, ss.w / 20.f);
                *(float4*)(vavg + oidx)  = make_float4(sv.x / 20.f, sv.y / 20.f,
                                                       sv.z / 20.f, sv.w / 20.f);
                *(float4*)(srec + oidx)  = s4;
            }
        }

        // ---- step boundary: make ballots visible, then everyone advances ----
        if (t < TLAST) grid.sync();
    }
}

extern "C" void kernel_launch(void* const* d_in, const int* in_sizes, int n_in,
                              void* d_out, int out_size, void* d_ws, size_t ws_size,
                              hipStream_t stream) {
    const float* ff   = (const float*)d_in[0];   // [128][200][4096] f32
    const float* W    = (const float*)d_in[1];   // [4096][4096] f32 (Wab_T)
    const float* rec0 = (const float*)d_in[2];   // [128][4096] f32
    float* out = (float*)d_out;                  // rates | volts_avg | spikes_rec

    unsigned long long* bits = (unsigned long long*)d_ws;  // 2*8192 u64 = 128 KB

    void* args[] = {(void*)&ff, (void*)&W, (void*)&rec0, (void*)&out, (void*)&bits};
    hipLaunchCooperativeKernel((const void*)lif_all, dim3(512), dim3(256),
                               args, 0, stream);
}

// Round 7
// 4375.747 us; speedup vs baseline: 3.1559x; 3.1559x over previous
//
#include <hip/hip_runtime.h>
#include <stdint.h>

#define NBATCH 128
#define NNEUR  4096
#define TLAST  180                      // outputs depend only on steps 0..180
#define DECAY  0.6065306597126334f      // float(exp(-0.5))

// ONE persistent kernel, ONE block per batch, ZERO cross-block sync.
// Block: 1024 threads = 16 waves; wave w owns cols [w*256, +256), 4 cols/lane
// (float4). The spike bitmask is BLOCK-PRIVATE (LDS) -> blocks free-run through
// all 181 steps with only two block-local __syncthreads per step.
// volts / rec / window sums live in registers for the entire run.
// slist construction order (ascending word, ascending bit) is identical to the
// multi-launch version -> bitwise-identical outputs.
__global__ __launch_bounds__(1024, 1) void lif_batch(
    const float* __restrict__ ff, const float* __restrict__ W,
    const float* __restrict__ rec0, float* __restrict__ out)
{
#pragma clang fp contract(off)          // match numpy's separate mul/add roundings
    __shared__ __align__(16) unsigned short slist[NNEUR];
    __shared__ unsigned long long bwords[NNEUR / 64];   // 64 u64 spike words
    __shared__ int scnt;

    const int tid  = threadIdx.x;
    const int lane = tid & 63;
    const int wid  = tid >> 6;
    const int b    = blockIdx.x;                      // batch
    const int n0   = ((wid << 6) + lane) << 2;        // lane's 4 columns
    const unsigned laneb = (unsigned)n0 * 4u;         // byte offset within a W row

    const char*  Wb   = (const char*)W;
    const float* fptr = ff + (((size_t)b * 200) << 12) + n0;
    const size_t idx  = ((size_t)b << 12) + (size_t)n0;

    float4 v4 = make_float4(0.f, 0.f, 0.f, 0.f);      // volts (regs, whole run)
    float4 r4 = *(const float4*)(rec0 + idx);         // rec
    float4 ss = v4, sv = v4;                          // window sums

    for (int t = 0; t <= TLAST; ++t) {
        const float4 f4 = *(const float4*)fptr;       // independent: overlaps gather
        fptr += NNEUR;

        float4 acc = make_float4(0.f, 0.f, 0.f, 0.f);
        if (t > 0) {
            // ---- decode block's spike words into LDS index list (wave 0) ----
            if (wid == 0) {
                unsigned long long m = bwords[lane];            // word `lane`
                const int c = __popcll(m);
                int x = c;
                #pragma unroll
                for (int o = 1; o < 64; o <<= 1) {
                    int y = __shfl_up(x, (unsigned)o);
                    if (lane >= o) x += y;
                }
                if (lane == 63) scnt = x;
                int widx = x - c;                               // exclusive prefix
                const int jb = ((lane >> 2) << 8) + (lane & 3); // word's col base
                while (m) {
                    const int u = __builtin_ctzll(m);
                    m &= m - 1;
                    slist[widx++] = (unsigned short)(jb + (u << 2));
                }
            }
            __syncthreads();                          // slist ready

            // ---- sparse gather: 4+4 double-buffered float4 pipeline ----
            const int cnt = scnt;
            auto load4 = [&](float4* R, int ii) {
                const uint2 pk = *(const uint2*)(slist + ii);
                const unsigned qa = __builtin_amdgcn_readfirstlane(pk.x);
                const unsigned qb = __builtin_amdgcn_readfirstlane(pk.y);
                R[0] = *(const float4*)(Wb + (((qa & 0xffffu) << 14) + laneb));
                R[1] = *(const float4*)(Wb + (((qa >> 16)     << 14) + laneb));
                R[2] = *(const float4*)(Wb + (((qb & 0xffffu) << 14) + laneb));
                R[3] = *(const float4*)(Wb + (((qb >> 16)     << 14) + laneb));
            };
            auto acc4 = [&](const float4* R) {
                #pragma unroll
                for (int k = 0; k < 4; ++k) {
                    acc.x += R[k].x; acc.y += R[k].y;
                    acc.z += R[k].z; acc.w += R[k].w;
                }
            };

            int i = 0;
            if (cnt >= 4) {
                float4 A[4], B[4];
                load4(A, 0); i = 4;
                while (i + 8 <= cnt) {
                    load4(B, i);     acc4(A);
                    load4(A, i + 4); acc4(B);
                    i += 8;
                }
                if (i + 4 <= cnt) { load4(B, i); acc4(A); acc4(B); i += 4; }
                else              { acc4(A); }
            }
            for (; i < cnt; ++i) {
                unsigned q = (unsigned)slist[i];
                q = __builtin_amdgcn_readfirstlane(q);
                const float4 wv = *(const float4*)(Wb + ((q << 14) + laneb));
                acc.x += wv.x; acc.y += wv.y; acc.z += wv.z; acc.w += wv.w;
            }
        }

        // ---- elementwise LIF update (exact numpy op order) ----
        r4.x = r4.x * DECAY + acc.x * 0.5f;
        r4.y = r4.y * DECAY + acc.y * 0.5f;
        r4.z = r4.z * DECAY + acc.z * 0.5f;
        r4.w = r4.w * DECAY + acc.w * 0.5f;

        v4.x = v4.x * DECAY + 0.5f * (f4.x + r4.x);
        v4.y = v4.y * DECAY + 0.5f * (f4.y + r4.y);
        v4.z = v4.z * DECAY + 0.5f * (f4.z + r4.z);
        v4.w = v4.w * DECAY + 0.5f * (f4.w + r4.w);

        const bool s0 = v4.x >= 1.0f, s1 = v4.y >= 1.0f,
                   s2 = v4.z >= 1.0f, s3 = v4.w >= 1.0f;
        if (s0) v4.x = 0.f;
        if (s1) v4.y = 0.f;
        if (s2) v4.z = 0.f;
        if (s3) v4.w = 0.f;

        // ---- new spike words into block-private LDS ----
        const unsigned long long m0 = __ballot(s0), m1 = __ballot(s1),
                                 m2 = __ballot(s2), m3 = __ballot(s3);

        // ---- recording windows (sums in registers) ----
        if (t >= 80) {
            const float4 s4 = make_float4(s0 ? 1.f : 0.f, s1 ? 1.f : 0.f,
                                          s2 ? 1.f : 0.f, s3 ? 1.f : 0.f);
            const bool start = (t == 80) || (t == 101) || (t == 121) ||
                               (t == 141) || (t == 161);
            if (start) {
                ss = s4; sv = v4;
            } else {
                ss.x += s4.x; ss.y += s4.y; ss.z += s4.z; ss.w += s4.w;
                sv.x += v4.x; sv.y += v4.y; sv.z += v4.z; sv.w += v4.w;
            }
            if (t == 100 || t == 120 || t == 140 || t == 160 || t == 180) {
                const int k = (t - 100) / 20;
                const size_t oidx = (((size_t)b * 5 + (size_t)k) << 12) + n0;
                float* rates = out;
                float* vavg  = out + (size_t)NBATCH * 5 * NNEUR;
                float* srec  = out + (size_t)NBATCH * 5 * NNEUR * 2;
                *(float4*)(rates + oidx) = make_float4(ss.x / 20.f, ss.y / 20.f,
                                                       ss.z / 20.f, ss.w / 20.f);
                *(float4*)(vavg + oidx)  = make_float4(sv.x / 20.f, sv.y / 20.f,
                                                       sv.z / 20.f, sv.w / 20.f);
                *(float4*)(srec + oidx)  = s4;
            }
        }

        if (t < TLAST) {
            if (lane == 0) {
                unsigned long long* dst = bwords + (wid << 2);  // n0 range /64
                dst[0] = m0; dst[1] = m1; dst[2] = m2; dst[3] = m3;
            }
            __syncthreads();    // words visible for next decode; slist safe to reuse
        }
    }
}

extern "C" void kernel_launch(void* const* d_in, const int* in_sizes, int n_in,
                              void* d_out, int out_size, void* d_ws, size_t ws_size,
                              hipStream_t stream) {
    const float* ff   = (const float*)d_in[0];   // [128][200][4096] f32
    const float* W    = (const float*)d_in[1];   // [4096][4096] f32 (Wab_T)
    const float* rec0 = (const float*)d_in[2];   // [128][4096] f32
    float* out = (float*)d_out;                  // rates | volts_avg | spikes_rec

    lif_batch<<<dim3(NBATCH), dim3(1024), 0, stream>>>(ff, W, rec0, out);
}